// Round 1
// baseline (299.038 us; speedup 1.0000x reference)
//
#include <hip/hip_runtime.h>
#include <hip/hip_bf16.h>

#define BB 8
#define SS 2048
#define NN 1024
#define MT (BB*SS)   // 16384
#define NPC 32       // partial chunks per row (8 kc-tiles * 4 wave-columns)
#define NG 16        // K groups of 64

typedef __attribute__((ext_vector_type(8))) short bf16x8;
typedef __attribute__((ext_vector_type(4))) float f32x4;
typedef unsigned short u16;
typedef unsigned int u32;

__device__ __forceinline__ u16 f2bf(float f) {
  u32 u = __float_as_uint(f);
  u += 0x7fff + ((u >> 16) & 1);
  return (u16)(u >> 16);
}
__device__ __forceinline__ float bf2f(u16 h) {
  return __uint_as_float(((u32)h) << 16);
}

typedef __attribute__((address_space(1))) void GV;
typedef __attribute__((address_space(3))) void LV;
__device__ __forceinline__ void cp16(const void* g, void* l) {
  __builtin_amdgcn_global_load_lds((GV*)g, (LV*)l, 16, 0, 0);
}

#define WAITV8 asm volatile("s_waitcnt vmcnt(8)" ::: "memory")
#define WAITV0 asm volatile("s_waitcnt vmcnt(0)" ::: "memory")
#define BARX   __builtin_amdgcn_s_barrier()
#define FEN    asm volatile("" ::: "memory")

// ------- prep: cast outer -> bf16, rowsum -> r, kb init = mask (1 wave/row) --
__global__ __launch_bounds__(256) void prep_x_kernel(const float* __restrict__ outer,
                                                     const float* __restrict__ mask,
                                                     u16* __restrict__ Xb,
                                                     float* __restrict__ r,
                                                     float* __restrict__ kb) {
  int w = threadIdx.x >> 6, lane = threadIdx.x & 63;
  int row = blockIdx.x * 4 + w;
  const float4* src = (const float4*)(outer + (size_t)row * NN);
  ushort4* dst = (ushort4*)(Xb + (size_t)row * NN);
  float s = 0.f;
#pragma unroll
  for (int u = 0; u < 4; u++) {
    int idx = lane + u * 64;
    float4 v = src[idx];
    ushort4 o;
    o.x = f2bf(v.x); o.y = f2bf(v.y); o.z = f2bf(v.z); o.w = f2bf(v.w);
    dst[idx] = o;
    s += (v.x + v.y) + (v.z + v.w);
  }
#pragma unroll
  for (int off = 1; off < 64; off <<= 1) s += __shfl_xor(s, off);
  if (lane == 0) { r[row] = s; kb[row] = mask[row]; }
}

// ---------------- prep: cast weights -> bf16 (rows 0..1023 = Wq, 1024.. = Wk) --
__global__ __launch_bounds__(256) void prep_w_kernel(const float* __restrict__ Wq,
                                                     const float* __restrict__ Wk,
                                                     const float* __restrict__ bq,
                                                     const float* __restrict__ bk,
                                                     u16* __restrict__ Wb,
                                                     float* __restrict__ bb) {
  int idx = blockIdx.x * 256 + threadIdx.x;   // 0 .. 524287 (x4 elems)
  int e = idx * 4;
  int rowm = e >> 10;
  int col = e & 1023;
  const float* srcp = (rowm < NN) ? (Wq + (size_t)rowm * NN + col)
                                  : (Wk + (size_t)(rowm - NN) * NN + col);
  float4 v = *(const float4*)srcp;
  ushort4 o; o.x = f2bf(v.x); o.y = f2bf(v.y); o.z = f2bf(v.z); o.w = f2bf(v.w);
  *(ushort4*)(Wb + (size_t)e) = o;
  if (idx < 2 * NN) bb[idx] = (idx < NN) ? bq[idx] : bk[idx - NN];
}

// ---------------- shared 256x256 / BK=64 / ring-2 counted-vmcnt GEMM core ----
// LDS layout per operand: [slot(2)][ksub(2)][256 rows][32 cols] bf16 = 64 KB.
// 64B rows -> even bank spread on ds_read_b128 (measured-negligible conflicts).
// Stage of K-tile k+1 is issued BEFORE computing k; vmcnt(8) (one stage's
// per-wave load count) keeps it in flight across the MFMA block. Race-free:
// stage(k+1) targets slot((k+1)&1), whose last ds_reads (group k-1) completed
// before group k-1's end barrier, which precedes this issue point.
template<int LDG>
__device__ __forceinline__ void gemm_core(const u16* gA0, const u16* gB0,
                                          u16* lA, u16* lB, int tid,
                                          f32x4 (&acc)[8][4]) {
  const int row_t = tid >> 2;          // 0..127
  const int c8 = (tid & 3) << 3;       // elem offset in 32-col slice
  const int lane = tid & 63;
  const int w = tid >> 6;
  const int wr = w >> 2, wc = w & 3;   // 2 M-groups x 4 N-groups
  const int l15 = lane & 15, quad = lane >> 4;
  const u16* sA = gA0 + (size_t)row_t * LDG + c8;
  const u16* sB = gB0 + (size_t)row_t * LDG + c8;
  u16* dA = lA + row_t * 32 + c8;      // linear dest: byte off == tid*16
  u16* dB = lB + row_t * 32 + c8;
  const u16* pa = lA + (wr * 128 + l15) * 32 + quad * 8;
  const u16* pb = lB + (wc * 64 + l15) * 32 + quad * 8;

  auto STAGE = [&](int s, int kt) {
    const u16* a_ = sA + kt * 64;
    const u16* b_ = sB + kt * 64;
    u16* la_ = dA + s * 16384;
    u16* lb_ = dB + s * 16384;
    cp16(a_, la_);                cp16(a_ + 128 * LDG, la_ + 4096);
    cp16(a_ + 32, la_ + 8192);    cp16(a_ + 32 + 128 * LDG, la_ + 12288);
    cp16(b_, lb_);                cp16(b_ + 128 * LDG, lb_ + 4096);
    cp16(b_ + 32, lb_ + 8192);    cp16(b_ + 32 + 128 * LDG, lb_ + 12288);
  };

  auto COMP = [&](int s) {
#pragma unroll
    for (int ks = 0; ks < 2; ++ks) {
      bf16x8 af[8], bf[4];
#pragma unroll
      for (int i = 0; i < 8; ++i) af[i] = *(const bf16x8*)(pa + s * 16384 + ks * 8192 + i * 512);
#pragma unroll
      for (int j = 0; j < 4; ++j) bf[j] = *(const bf16x8*)(pb + s * 16384 + ks * 8192 + j * 512);
      __builtin_amdgcn_s_setprio(1);
#pragma unroll
      for (int i = 0; i < 8; ++i)
#pragma unroll
        for (int j = 0; j < 4; ++j)
          acc[i][j] = __builtin_amdgcn_mfma_f32_16x16x32_bf16(af[i], bf[j], acc[i][j], 0, 0, 0);
      __builtin_amdgcn_s_setprio(0);
    }
  };

  STAGE(0, 0);
#pragma unroll 1
  for (int k = 0; k < NG - 2; k += 2) {
    STAGE(1, k + 1); WAITV8; BARX; FEN; COMP(0); BARX;
    STAGE(0, k + 2); WAITV8; BARX; FEN; COMP(1); BARX;
  }
  STAGE(1, NG - 1); WAITV8; BARX; FEN; COMP(0); BARX;
  WAITV0; BARX; FEN; COMP(1);
}

// ---------------- stage 1 GEMM: C[row][m] = sigmoid(X.Wb^T + bb) - 0.5 (bf16) --
__global__ __launch_bounds__(512, 2) void gemm1_kernel(const u16* __restrict__ X,
                                                       const u16* __restrict__ W,
                                                       const float* __restrict__ bb,
                                                       u16* __restrict__ C,
                                                       float* __restrict__ kb) {
  __shared__ u16 lA[2 * 16384];
  __shared__ u16 lB[2 * 16384];
  int bid = blockIdx.x;                 // 512
  int xcd = bid & 7, idx = bid >> 3;    // XCD-affine: per-XCD 8 tm x 8 tn panel
  int tm = xcd * 8 + (idx & 7);         // 0..63
  int tn = idx >> 3;                    // 0..7
  int tid = threadIdx.x;
  f32x4 acc[8][4] = {};
  gemm_core<1024>(X + (size_t)tm * 256 * 1024, W + (size_t)tn * 256 * 1024,
                  lA, lB, tid, acc);

  int lane = tid & 63, w = tid >> 6;
  int wr = w >> 2, wc = w & 3, l15 = lane & 15, quad = lane >> 4;
  int colb = tn * 256 + wc * 64 + l15;
  bool khalf = (tn >= 4);               // whole tile in k' half when tn>=4
  int rowb = tm * 256 + wr * 128 + quad * 4;
#pragma unroll
  for (int i = 0; i < 8; ++i) {
    float rsum[4] = {0.f, 0.f, 0.f, 0.f};
#pragma unroll
    for (int j = 0; j < 4; ++j) {
      int col = colb + j * 16;
      float bias = bb[col];
#pragma unroll
      for (int rg = 0; rg < 4; ++rg) {
        int row = rowb + i * 16 + rg;
        float v = acc[i][j][rg] + bias;
        float sg = 1.0f / (1.0f + __expf(-v));
        u16 h = f2bf(sg - 0.5f);
        C[(size_t)row * 2048 + col] = h;
        rsum[rg] += bf2f(h);   // rounded value, matches what flash's MFMA sees
      }
    }
    if (khalf) {
#pragma unroll
      for (int rg = 0; rg < 4; ++rg) {
        float s = rsum[rg];
#pragma unroll
        for (int off = 1; off < 16; off <<= 1) s += __shfl_xor(s, off);
        if (l15 == 0) atomicAdd(&kb[rowb + i * 16 + rg], 0.5f * s);
      }
    }
  }
}

// ---------------- flash: one 256q x 256k tile per block; XCD = batch ----
__global__ __launch_bounds__(512, 2) void flash_kernel(const u16* __restrict__ Cq,
                                                       const float* __restrict__ kb,
                                                       const float* __restrict__ r,
                                                       float* __restrict__ pm,
                                                       float* __restrict__ pl,
                                                       float* __restrict__ pt) {
  __shared__ u16 lA[2 * 16384];
  __shared__ u16 lB[2 * 16384];
  int bid = blockIdx.x;            // 512
  int b = bid & 7;                 // XCD-affine: each XCD owns one batch
  int idx = bid >> 3;
  int qt = idx >> 3;               // 0..7
  int kc = idx & 7;                // inner: q-tile reused from L2
  int tid = threadIdx.x;
  f32x4 acc[8][4] = {};
  gemm_core<2048>(Cq + (size_t)(b * SS + qt * 256) * 2048,
                  Cq + (size_t)(b * SS + kc * 256) * 2048 + 1024,
                  lA, lB, tid, acc);

  int lane = tid & 63, w = tid >> 6;
  int wr = w >> 2, wc = w & 3, l15 = lane & 15, quad = lane >> 4;
  float kbv[4], rv[4];
  int colg = b * SS + kc * 256 + wc * 64 + l15;
#pragma unroll
  for (int j = 0; j < 4; ++j) { kbv[j] = kb[colg + j * 16]; rv[j] = r[colg + j * 16]; }
  int chunk = kc * 4 + wc;
  int rowb = b * SS + qt * 256 + wr * 128 + quad * 4;
#pragma unroll
  for (int i = 0; i < 8; ++i) {
#pragma unroll
    for (int rg = 0; rg < 4; ++rg) {
      float lg[4];
      float tmax = -1e30f;
#pragma unroll
      for (int j = 0; j < 4; ++j) { lg[j] = acc[i][j][rg] + kbv[j]; tmax = fmaxf(tmax, lg[j]); }
#pragma unroll
      for (int off = 1; off < 16; off <<= 1) tmax = fmaxf(tmax, __shfl_xor(tmax, off));
      float rs = 0.f, rt = 0.f;
#pragma unroll
      for (int j = 0; j < 4; ++j) {
        float p = __expf(lg[j] - tmax);
        rs += p; rt += p * rv[j];
      }
#pragma unroll
      for (int off = 1; off < 16; off <<= 1) { rs += __shfl_xor(rs, off); rt += __shfl_xor(rt, off); }
      if (l15 == 0) {
        int grow = rowb + i * 16 + rg;
        pm[(size_t)grow * NPC + chunk] = tmax;
        pl[(size_t)grow * NPC + chunk] = rs;
        pt[(size_t)grow * NPC + chunk] = rt;
      }
    }
  }
}

// ---------------- combine key-chunk partials ----------------
__global__ __launch_bounds__(256) void fixup_kernel(const float* __restrict__ pm,
                                                    const float* __restrict__ pl,
                                                    const float* __restrict__ pt,
                                                    float* __restrict__ out) {
  int row = blockIdx.x * 256 + threadIdx.x;
  float Mx = -1e30f;
#pragma unroll
  for (int c = 0; c < NPC; c++) Mx = fmaxf(Mx, pm[row * NPC + c]);
  float L = 0.f, T = 0.f;
#pragma unroll
  for (int c = 0; c < NPC; c++) {
    float a = __expf(pm[row * NPC + c] - Mx);
    L += pl[row * NPC + c] * a;
    T += pt[row * NPC + c] * a;
  }
  out[row] = T / L;
}

extern "C" void kernel_launch(void* const* d_in, const int* in_sizes, int n_in,
                              void* d_out, int out_size, void* d_ws, size_t ws_size,
                              hipStream_t stream) {
  const float* outer = (const float*)d_in[0];
  const float* mask  = (const float*)d_in[1];
  const float* Wk    = (const float*)d_in[2];
  const float* bk    = (const float*)d_in[3];
  const float* Wq    = (const float*)d_in[4];
  const float* bq    = (const float*)d_in[5];
  float* out = (float*)d_out;

  char* ws = (char*)d_ws;
  size_t off = 0;
  auto alloc = [&](size_t bytes) -> void* {
    void* p = ws + off;
    off = (off + bytes + 255) & ~(size_t)255;
    return p;
  };
  u16* Xb  = (u16*)alloc((size_t)MT * NN * 2);       // 32 MB bf16 outer
  u16* Wb  = (u16*)alloc((size_t)2048 * NN * 2);     // 4 MB bf16 [Wq;Wk]
  u16* Cq  = (u16*)alloc((size_t)MT * 2048 * 2);     // 64 MB bf16 [q'|k']
  float* bb = (float*)alloc(2048 * 4);
  float* rr = (float*)alloc((size_t)MT * 4);
  float* kb = (float*)alloc((size_t)MT * 4);
  float* pm = (float*)alloc((size_t)MT * NPC * 4);
  float* pl = (float*)alloc((size_t)MT * NPC * 4);
  float* pt = (float*)alloc((size_t)MT * NPC * 4);

  prep_x_kernel<<<dim3(MT / 4), dim3(256), 0, stream>>>(outer, mask, Xb, rr, kb);
  prep_w_kernel<<<dim3(2048), dim3(256), 0, stream>>>(Wq, Wk, bq, bk, Wb, bb);
  gemm1_kernel<<<dim3(512), dim3(512), 0, stream>>>(Xb, Wb, bb, Cq, kb);
  flash_kernel<<<dim3(512), dim3(512), 0, stream>>>(Cq, kb, rr, pm, pl, pt);
  fixup_kernel<<<dim3(MT / 256), dim3(256), 0, stream>>>(pm, pl, pt, out);
}

// Round 2
// 283.872 us; speedup vs baseline: 1.0534x; 1.0534x over previous
//
#include <hip/hip_runtime.h>
#include <hip/hip_bf16.h>

#define BB 8
#define SS 2048
#define NN 1024
#define MT (BB*SS)   // 16384
#define NPC 32       // partial chunks per row (8 kc-tiles * 4 wave-columns)
#define NT 16        // K tiles of 64

typedef __attribute__((ext_vector_type(8))) short bf16x8;
typedef __attribute__((ext_vector_type(4))) float f32x4;
typedef unsigned short u16;
typedef unsigned int u32;

__device__ __forceinline__ u16 f2bf(float f) {
  u32 u = __float_as_uint(f);
  u += 0x7fff + ((u >> 16) & 1);
  return (u16)(u >> 16);
}
__device__ __forceinline__ float bf2f(u16 h) {
  return __uint_as_float(((u32)h) << 16);
}

typedef __attribute__((address_space(1))) void GV;
typedef __attribute__((address_space(3))) void LV;
__device__ __forceinline__ void cp16(const void* g, void* l) {
  __builtin_amdgcn_global_load_lds((GV*)g, (LV*)l, 16, 0, 0);
}

#define WAIT4 asm volatile("s_waitcnt vmcnt(4)" ::: "memory")
#define WAIT6 asm volatile("s_waitcnt vmcnt(6)" ::: "memory")
#define LGKM0 asm volatile("s_waitcnt lgkmcnt(0)" ::: "memory")
#define BARX  __builtin_amdgcn_s_barrier()
#define SCB0  __builtin_amdgcn_sched_barrier(0)

// ------- prep: cast outer -> bf16, rowsum -> r, kb init = mask (1 wave/row) --
__global__ __launch_bounds__(256) void prep_x_kernel(const float* __restrict__ outer,
                                                     const float* __restrict__ mask,
                                                     u16* __restrict__ Xb,
                                                     float* __restrict__ r,
                                                     float* __restrict__ kb) {
  int w = threadIdx.x >> 6, lane = threadIdx.x & 63;
  int row = blockIdx.x * 4 + w;
  const float4* src = (const float4*)(outer + (size_t)row * NN);
  ushort4* dst = (ushort4*)(Xb + (size_t)row * NN);
  float s = 0.f;
#pragma unroll
  for (int u = 0; u < 4; u++) {
    int idx = lane + u * 64;
    float4 v = src[idx];
    ushort4 o;
    o.x = f2bf(v.x); o.y = f2bf(v.y); o.z = f2bf(v.z); o.w = f2bf(v.w);
    dst[idx] = o;
    s += (v.x + v.y) + (v.z + v.w);
  }
#pragma unroll
  for (int off = 1; off < 64; off <<= 1) s += __shfl_xor(s, off);
  if (lane == 0) { r[row] = s; kb[row] = mask[row]; }
}

// ---------------- prep: cast weights -> bf16 (rows 0..1023 = Wq, 1024.. = Wk) --
__global__ __launch_bounds__(256) void prep_w_kernel(const float* __restrict__ Wq,
                                                     const float* __restrict__ Wk,
                                                     const float* __restrict__ bq,
                                                     const float* __restrict__ bk,
                                                     u16* __restrict__ Wb,
                                                     float* __restrict__ bb) {
  int idx = blockIdx.x * 256 + threadIdx.x;   // 0 .. 524287 (x4 elems)
  int e = idx * 4;
  int rowm = e >> 10;
  int col = e & 1023;
  const float* srcp = (rowm < NN) ? (Wq + (size_t)rowm * NN + col)
                                  : (Wk + (size_t)(rowm - NN) * NN + col);
  float4 v = *(const float4*)srcp;
  ushort4 o; o.x = f2bf(v.x); o.y = f2bf(v.y); o.z = f2bf(v.z); o.w = f2bf(v.w);
  *(ushort4*)(Wb + (size_t)e) = o;
  if (idx < 2 * NN) bb[idx] = (idx < NN) ? bq[idx] : bk[idx - NN];
}

// ======= 256x256 / BK=64 / 4-phase-per-tile / counted-vmcnt GEMM core =======
// LDS per buf (64KB): A half0(16KB) A half1(16KB) Bq0..Bq3(8KB each). 2 bufs.
// Wave (wr,wc): reads A half wr (all 128 rows), B quarter wc (its 64 cols).
// STAGING is per-wave-role: each wave stages exactly the regions it reads
// (4 A-instr + 4 B-instr per K-tile, 2 per phase) in consumption order
// Aa,Ba,Bb,Ab -> its own vmcnt(4) before each barrier guarantees the data
// needed 3 phases later. Loads never drained to 0 inside the loop (T4).
// T2 swizzle: reader slot ^= (row&7); writer keeps LDS dest linear and
// pre-permutes the GLOBAL source column (same involution) per rule 21.
template<int LDG>
__device__ __forceinline__ void gemm_core(const u16* gA, const u16* gB,
                                          u16* lds, int tid,
                                          f32x4 (&acc)[8][4]) {
  const int lane = tid & 63, w = tid >> 6;
  const int wr = w >> 2, wc = w & 3;
  const int l15 = lane & 15, quad = lane >> 4, xq = l15 & 7;
  const int lr = lane >> 3, lc = lane & 7;
  const int sslot = lc ^ lr;                  // pre-swizzled src 16B-slot
  const int so0 = ((quad ^ xq)) * 8;          // ks=0 read slot offset (elems)
  const int so1 = (((4 + quad) ^ xq)) * 8;    // ks=1

  // global bases for this wave's staging role (row includes swizzle row part)
  const u16* gAr = gA + (size_t)(wr * 128 + wc * 8 + lr) * LDG + sslot * 8;
  const u16* gBr = gB + (size_t)(wc * 64 + wr * 8 + lr) * LDG + sslot * 8;

  auto STA = [&](int buf, int lo, int kt) {   // A-half wr, rows lo*32+wc*8+lr
    cp16(gAr + (size_t)lo * 32 * LDG + kt * 64,
         lds + buf * 32768 + wr * 8192 + ((lo * 4 + wc) * 64 + lane) * 8);
  };
  auto STB = [&](int buf, int lb, int kt) {   // B-quarter wc, rows lb*16+wr*8+lr
    cp16(gBr + (size_t)lb * 16 * LDG + kt * 64,
         lds + buf * 32768 + 16384 + wc * 4096 + ((lb * 2 + wr) * 64 + lane) * 8);
  };

  bf16x8 af[4][2], bf[2][2];
  auto LDA4 = [&](int buf, int ih) {
#pragma unroll
    for (int i2 = 0; i2 < 4; ++i2) {
      const u16* p = lds + buf * 32768 + wr * 8192 + (ih * 64 + i2 * 16 + l15) * 64;
      af[i2][0] = *(const bf16x8*)(p + so0);
      af[i2][1] = *(const bf16x8*)(p + so1);
    }
  };
  auto LDB2 = [&](int buf, int jh) {
#pragma unroll
    for (int j2 = 0; j2 < 2; ++j2) {
      const u16* p = lds + buf * 32768 + 16384 + wc * 4096 + ((jh * 2 + j2) * 16 + l15) * 64;
      bf[j2][0] = *(const bf16x8*)(p + so0);
      bf[j2][1] = *(const bf16x8*)(p + so1);
    }
  };
  auto MQ = [&](int ih, int jh) {
    __builtin_amdgcn_s_setprio(1);
#pragma unroll
    for (int ks = 0; ks < 2; ++ks)
#pragma unroll
      for (int i2 = 0; i2 < 4; ++i2)
#pragma unroll
        for (int j2 = 0; j2 < 2; ++j2)
          acc[ih * 4 + i2][jh * 2 + j2] =
              __builtin_amdgcn_mfma_f32_16x16x32_bf16(af[i2][ks], bf[j2][ks],
                                                      acc[ih * 4 + i2][jh * 2 + j2], 0, 0, 0);
    __builtin_amdgcn_s_setprio(0);
  };

  // prologue: tile 0 in consumption order Aa,Ba | Bb,Ab
  STA(0, 0, 0); STA(0, 1, 0); STB(0, 0, 0); STB(0, 1, 0);
  STB(0, 2, 0); STB(0, 3, 0); STA(0, 2, 0); STA(0, 3, 0);
  WAIT4; BARX;

#pragma unroll 1
  for (int t = 0; t < NT; ++t) {
    const int buf = t & 1, nb = buf ^ 1, nt = t + 1;
    const bool st = (t < NT - 1);
    // ---- ph1: read Aa(af ih0) + Ba(bf jh0); stage Aa' ----
    LDA4(buf, 0); LDB2(buf, 0);
    if (st) { STA(nb, 0, nt); STA(nb, 1, nt); }
    WAIT4; BARX; LGKM0; SCB0;
    MQ(0, 0);
    BARX;
    // ---- ph2: read Bb(bf jh1); stage Ba' ----
    LDB2(buf, 1);
    if (st) { STB(nb, 0, nt); STB(nb, 1, nt); }
    WAIT4; BARX; LGKM0; SCB0;
    MQ(0, 1);
    BARX;
    // ---- ph3: read Ab(af ih1); stage Bb' ----
    LDA4(buf, 1);
    if (st) { STB(nb, 2, nt); STB(nb, 3, nt); }
    WAIT6; BARX; LGKM0; SCB0;
    MQ(1, 1);
    BARX;
    // ---- ph4: re-read Ba(bf jh0); stage Ab' ----
    LDB2(buf, 0);
    if (st) { STA(nb, 2, nt); STA(nb, 3, nt); }
    WAIT4; BARX; LGKM0; SCB0;
    MQ(1, 0);
    BARX;
  }
}

// ---------------- stage 1 GEMM: C[row][m] = sigmoid(X.Wb^T + bb) - 0.5 (bf16) --
__global__ __launch_bounds__(512, 2) void gemm1_kernel(const u16* __restrict__ X,
                                                       const u16* __restrict__ W,
                                                       const float* __restrict__ bb,
                                                       u16* __restrict__ C,
                                                       float* __restrict__ kb) {
  __shared__ u16 lds[2 * 32768];
  int bid = blockIdx.x;                 // 512
  int xcd = bid & 7, idx = bid >> 3;    // XCD-affine: per-XCD 8 tm x 8 tn panel
  int tm = xcd * 8 + (idx & 7);         // 0..63
  int tn = idx >> 3;                    // 0..7
  int tid = threadIdx.x;
  f32x4 acc[8][4] = {};
  gemm_core<1024>(X + (size_t)tm * 256 * 1024, W + (size_t)tn * 256 * 1024,
                  lds, tid, acc);

  int lane = tid & 63, w = tid >> 6;
  int wr = w >> 2, wc = w & 3, l15 = lane & 15, quad = lane >> 4;
  int colb = tn * 256 + wc * 64 + l15;
  bool khalf = (tn >= 4);               // whole tile in k' half when tn>=4
  int rowb = tm * 256 + wr * 128 + quad * 4;
#pragma unroll
  for (int i = 0; i < 8; ++i) {
    float rsum[4] = {0.f, 0.f, 0.f, 0.f};
#pragma unroll
    for (int j = 0; j < 4; ++j) {
      int col = colb + j * 16;
      float bias = bb[col];
#pragma unroll
      for (int rg = 0; rg < 4; ++rg) {
        int row = rowb + i * 16 + rg;
        float v = acc[i][j][rg] + bias;
        float sg = 1.0f / (1.0f + __expf(-v));
        u16 h = f2bf(sg - 0.5f);
        C[(size_t)row * 2048 + col] = h;
        rsum[rg] += bf2f(h);   // rounded value, matches what flash's MFMA sees
      }
    }
    if (khalf) {
#pragma unroll
      for (int rg = 0; rg < 4; ++rg) {
        float s = rsum[rg];
#pragma unroll
        for (int off = 1; off < 16; off <<= 1) s += __shfl_xor(s, off);
        if (l15 == 0) atomicAdd(&kb[rowb + i * 16 + rg], 0.5f * s);
      }
    }
  }
}

// ---------------- flash: one 256q x 256k tile per block; XCD = batch ----
__global__ __launch_bounds__(512, 2) void flash_kernel(const u16* __restrict__ Cq,
                                                       const float* __restrict__ kb,
                                                       const float* __restrict__ r,
                                                       float* __restrict__ pm,
                                                       float* __restrict__ pl,
                                                       float* __restrict__ pt) {
  __shared__ u16 lds[2 * 32768];
  int bid = blockIdx.x;            // 512
  int b = bid & 7;                 // XCD-affine: each XCD owns one batch
  int idx = bid >> 3;
  int qt = idx >> 3;               // 0..7
  int kc = idx & 7;                // inner: q-tile reused from L2
  int tid = threadIdx.x;
  f32x4 acc[8][4] = {};
  gemm_core<2048>(Cq + (size_t)(b * SS + qt * 256) * 2048,
                  Cq + (size_t)(b * SS + kc * 256) * 2048 + 1024,
                  lds, tid, acc);

  int lane = tid & 63, w = tid >> 6;
  int wr = w >> 2, wc = w & 3, l15 = lane & 15, quad = lane >> 4;
  float kbv[4], rv[4];
  int colg = b * SS + kc * 256 + wc * 64 + l15;
#pragma unroll
  for (int j = 0; j < 4; ++j) { kbv[j] = kb[colg + j * 16]; rv[j] = r[colg + j * 16]; }
  int chunk = kc * 4 + wc;
  int rowb = b * SS + qt * 256 + wr * 128 + quad * 4;
#pragma unroll
  for (int i = 0; i < 8; ++i) {
#pragma unroll
    for (int rg = 0; rg < 4; ++rg) {
      float lg[4];
      float tmax = -1e30f;
#pragma unroll
      for (int j = 0; j < 4; ++j) { lg[j] = acc[i][j][rg] + kbv[j]; tmax = fmaxf(tmax, lg[j]); }
#pragma unroll
      for (int off = 1; off < 16; off <<= 1) tmax = fmaxf(tmax, __shfl_xor(tmax, off));
      float rs = 0.f, rt = 0.f;
#pragma unroll
      for (int j = 0; j < 4; ++j) {
        float p = __expf(lg[j] - tmax);
        rs += p; rt += p * rv[j];
      }
#pragma unroll
      for (int off = 1; off < 16; off <<= 1) { rs += __shfl_xor(rs, off); rt += __shfl_xor(rt, off); }
      if (l15 == 0) {
        int grow = rowb + i * 16 + rg;
        pm[(size_t)grow * NPC + chunk] = tmax;
        pl[(size_t)grow * NPC + chunk] = rs;
        pt[(size_t)grow * NPC + chunk] = rt;
      }
    }
  }
}

// ---------------- combine key-chunk partials ----------------
__global__ __launch_bounds__(256) void fixup_kernel(const float* __restrict__ pm,
                                                    const float* __restrict__ pl,
                                                    const float* __restrict__ pt,
                                                    float* __restrict__ out) {
  int row = blockIdx.x * 256 + threadIdx.x;
  float Mx = -1e30f;
#pragma unroll
  for (int c = 0; c < NPC; c++) Mx = fmaxf(Mx, pm[row * NPC + c]);
  float L = 0.f, T = 0.f;
#pragma unroll
  for (int c = 0; c < NPC; c++) {
    float a = __expf(pm[row * NPC + c] - Mx);
    L += pl[row * NPC + c] * a;
    T += pt[row * NPC + c] * a;
  }
  out[row] = T / L;
}

extern "C" void kernel_launch(void* const* d_in, const int* in_sizes, int n_in,
                              void* d_out, int out_size, void* d_ws, size_t ws_size,
                              hipStream_t stream) {
  const float* outer = (const float*)d_in[0];
  const float* mask  = (const float*)d_in[1];
  const float* Wk    = (const float*)d_in[2];
  const float* bk    = (const float*)d_in[3];
  const float* Wq    = (const float*)d_in[4];
  const float* bq    = (const float*)d_in[5];
  float* out = (float*)d_out;

  char* ws = (char*)d_ws;
  size_t off = 0;
  auto alloc = [&](size_t bytes) -> void* {
    void* p = ws + off;
    off = (off + bytes + 255) & ~(size_t)255;
    return p;
  };
  u16* Xb  = (u16*)alloc((size_t)MT * NN * 2);       // 32 MB bf16 outer
  u16* Wb  = (u16*)alloc((size_t)2048 * NN * 2);     // 4 MB bf16 [Wq;Wk]
  u16* Cq  = (u16*)alloc((size_t)MT * 2048 * 2);     // 64 MB bf16 [q'|k']
  float* bb = (float*)alloc(2048 * 4);
  float* rr = (float*)alloc((size_t)MT * 4);
  float* kb = (float*)alloc((size_t)MT * 4);
  float* pm = (float*)alloc((size_t)MT * NPC * 4);
  float* pl = (float*)alloc((size_t)MT * NPC * 4);
  float* pt = (float*)alloc((size_t)MT * NPC * 4);

  prep_x_kernel<<<dim3(MT / 4), dim3(256), 0, stream>>>(outer, mask, Xb, rr, kb);
  prep_w_kernel<<<dim3(2048), dim3(256), 0, stream>>>(Wq, Wk, bq, bk, Wb, bb);
  gemm1_kernel<<<dim3(512), dim3(512), 0, stream>>>(Xb, Wb, bb, Cq, kb);
  flash_kernel<<<dim3(512), dim3(512), 0, stream>>>(Cq, kb, rr, pm, pl, pt);
  fixup_kernel<<<dim3(MT / 256), dim3(256), 0, stream>>>(pm, pl, pt, out);
}

// Round 3
// 270.920 us; speedup vs baseline: 1.1038x; 1.0478x over previous
//
#include <hip/hip_runtime.h>
#include <hip/hip_bf16.h>

#define BB 8
#define SS 2048
#define NN 1024
#define MT (BB*SS)   // 16384
#define NPC 32       // partial chunks per row (8 kc-tiles * 4 wave-columns)
#define NT 16        // K tiles of 64

typedef __attribute__((ext_vector_type(8))) short bf16x8;
typedef __attribute__((ext_vector_type(4))) float f32x4;
typedef unsigned short u16;
typedef unsigned int u32;

__device__ __forceinline__ u16 f2bf(float f) {
  u32 u = __float_as_uint(f);
  u += 0x7fff + ((u >> 16) & 1);
  return (u16)(u >> 16);
}
__device__ __forceinline__ float bf2f(u16 h) {
  return __uint_as_float(((u32)h) << 16);
}

typedef __attribute__((address_space(1))) void GV;
typedef __attribute__((address_space(3))) void LV;
__device__ __forceinline__ void cp16(const void* g, void* l) {
  __builtin_amdgcn_global_load_lds((GV*)g, (LV*)l, 16, 0, 0);
}

#define WAIT4 asm volatile("s_waitcnt vmcnt(4)" ::: "memory")
#define WAIT0 asm volatile("s_waitcnt vmcnt(0)" ::: "memory")
#define LGKM0 asm volatile("s_waitcnt lgkmcnt(0)" ::: "memory")
#define BARX  __builtin_amdgcn_s_barrier()
#define SCB0  __builtin_amdgcn_sched_barrier(0)

// ------- prep: cast outer -> bf16, rowsum -> r, kb init = mask (1 wave/row) --
__global__ __launch_bounds__(256) void prep_x_kernel(const float* __restrict__ outer,
                                                     const float* __restrict__ mask,
                                                     u16* __restrict__ Xb,
                                                     float* __restrict__ r,
                                                     float* __restrict__ kb) {
  int w = threadIdx.x >> 6, lane = threadIdx.x & 63;
  int row = blockIdx.x * 4 + w;
  const float4* src = (const float4*)(outer + (size_t)row * NN);
  ushort4* dst = (ushort4*)(Xb + (size_t)row * NN);
  float s = 0.f;
#pragma unroll
  for (int u = 0; u < 4; u++) {
    int idx = lane + u * 64;
    float4 v = src[idx];
    ushort4 o;
    o.x = f2bf(v.x); o.y = f2bf(v.y); o.z = f2bf(v.z); o.w = f2bf(v.w);
    dst[idx] = o;
    s += (v.x + v.y) + (v.z + v.w);
  }
#pragma unroll
  for (int off = 1; off < 64; off <<= 1) s += __shfl_xor(s, off);
  if (lane == 0) { r[row] = s; kb[row] = mask[row]; }
}

// ---------------- prep: cast weights -> bf16 (rows 0..1023 = Wq, 1024.. = Wk) --
__global__ __launch_bounds__(256) void prep_w_kernel(const float* __restrict__ Wq,
                                                     const float* __restrict__ Wk,
                                                     const float* __restrict__ bq,
                                                     const float* __restrict__ bk,
                                                     u16* __restrict__ Wb,
                                                     float* __restrict__ bb) {
  int idx = blockIdx.x * 256 + threadIdx.x;   // 0 .. 524287 (x4 elems)
  int e = idx * 4;
  int rowm = e >> 10;
  int col = e & 1023;
  const float* srcp = (rowm < NN) ? (Wq + (size_t)rowm * NN + col)
                                  : (Wk + (size_t)(rowm - NN) * NN + col);
  float4 v = *(const float4*)srcp;
  ushort4 o; o.x = f2bf(v.x); o.y = f2bf(v.y); o.z = f2bf(v.z); o.w = f2bf(v.w);
  *(ushort4*)(Wb + (size_t)e) = o;
  if (idx < 2 * NN) bb[idx] = (idx < NN) ? bq[idx] : bk[idx - NN];
}

// ======= 256x256 / BK=64 / 4-phase / region-ring-2 / ONE vmcnt per tile =======
// LDS per buf (64KB): A half0(16KB) A half1(16KB) Bq0..Bq3(8KB each). 2 bufs.
// Regions & last-read phase within a tile: A-lo{0,1}(rows0-63):ph2,
// A-lo{2,3}:ph4, B-lb{0,1}(jh0):ph2(reg-held to ph4), B-lb{2,3}(jh1):ph3.
// Stage schedule (per tile t): ph1: A1'(t+1)+B0'(t+1) [4 ld]; ph3: A0'(t+2)
// [2]; ph4: B1'(t+2) [2]  (t+2 shares buf parity with t; its regions' reads
// finished by ph2/ph3 and are lgkm-drained before the preceding barrier).
// ONE wait: vmcnt(4) at ph4 -> retires ALL tile-(t+1) regions (slack 3-5
// phases) and leaves tile-(t+2)'s 4 head loads in flight. Never drains
// except the t=14 tail. T2 swizzle identical to prev round (0 conflicts).
template<int LDG>
__device__ __forceinline__ void gemm_core(const u16* gA, const u16* gB,
                                          u16* lds, int tid,
                                          f32x4 (&acc)[8][4]) {
  const int lane = tid & 63, w = tid >> 6;
  const int wr = w >> 2, wc = w & 3;
  const int l15 = lane & 15, quad = lane >> 4, xq = l15 & 7;
  const int lr = lane >> 3, lc = lane & 7;
  const int sslot = lc ^ lr;                  // pre-swizzled src 16B-slot
  const int so0 = (quad ^ xq) * 8;            // ks=0 read slot offset (elems)
  const int so1 = ((4 + quad) ^ xq) * 8;      // ks=1

  const u16* gAr = gA + (size_t)(wr * 128 + wc * 8 + lr) * LDG + sslot * 8;
  const u16* gBr = gB + (size_t)(wc * 64 + wr * 8 + lr) * LDG + sslot * 8;

  u16* dA = lds + wr * 8192 + (wc * 64 + lane) * 8;          // +buf*32768+lo*2048
  u16* dB = lds + 16384 + wc * 4096 + wr * 512 + lane * 8;   // +buf*32768+lb*1024
  const u16* pA = lds + wr * 8192 + l15 * 64;                // +buf*32768+(ih*64+i2*16)*64
  const u16* pB = lds + 16384 + wc * 4096 + l15 * 64;        // +buf*32768+(jh*2+j2)*1024

  bf16x8 af[4][2], bf0[2][2], bf1[2][2];

  auto LDA = [&](int buf, int ih) {
#pragma unroll
    for (int i2 = 0; i2 < 4; ++i2) {
      const u16* p = pA + buf * 32768 + (ih * 64 + i2 * 16) * 64;
      af[i2][0] = *(const bf16x8*)(p + so0);
      af[i2][1] = *(const bf16x8*)(p + so1);
    }
  };
  auto LDB = [&](int buf, int jh, bf16x8 (&bf)[2][2]) {
#pragma unroll
    for (int j2 = 0; j2 < 2; ++j2) {
      const u16* p = pB + buf * 32768 + (jh * 2 + j2) * 1024;
      bf[j2][0] = *(const bf16x8*)(p + so0);
      bf[j2][1] = *(const bf16x8*)(p + so1);
    }
  };
  auto MQ = [&](int ih, int jh, bf16x8 (&bf)[2][2]) {
    __builtin_amdgcn_s_setprio(1);
#pragma unroll
    for (int ks = 0; ks < 2; ++ks)
#pragma unroll
      for (int i2 = 0; i2 < 4; ++i2)
#pragma unroll
        for (int j2 = 0; j2 < 2; ++j2)
          acc[ih * 4 + i2][jh * 2 + j2] =
              __builtin_amdgcn_mfma_f32_16x16x32_bf16(af[i2][ks], bf[j2][ks],
                                                      acc[ih * 4 + i2][jh * 2 + j2], 0, 0, 0);
    __builtin_amdgcn_s_setprio(0);
  };

  // prologue: tile0 full (8 ld) + A0'(1) (2) + B1'(1) (2); keep last 4 in flight
#pragma unroll
  for (int lo = 0; lo < 4; ++lo) cp16(gAr + (size_t)lo * 32 * LDG, dA + lo * 2048);
#pragma unroll
  for (int lb = 0; lb < 4; ++lb) cp16(gBr + (size_t)lb * 16 * LDG, dB + lb * 1024);
  cp16(gAr + 64,                          dA + 32768);           // A0'(1) lo=0
  cp16(gAr + (size_t)32 * LDG + 64,       dA + 32768 + 2048);    // lo=1
  cp16(gBr + (size_t)2 * 16 * LDG + 64,   dB + 32768 + 2048);    // B1'(1) lb=2
  cp16(gBr + (size_t)3 * 16 * LDG + 64,   dB + 32768 + 3072);    // lb=3
  WAIT4; BARX;

  const u16 *a1 = gAr + 64, *b1 = gBr + 64, *a2 = gAr + 128, *b2 = gBr + 128;

  auto TILE = [&](int buf, bool st1, bool st2) {
    const int nb = buf ^ 1;
    // ---- ph1: quadrant (0,0); stage A1'(t+1) + B0'(t+1) ----
    LDA(buf, 0); LDB(buf, 0, bf0);
    if (st1) {
      cp16(a1 + (size_t)2 * 32 * LDG, dA + nb * 32768 + 2 * 2048);
      cp16(a1 + (size_t)3 * 32 * LDG, dA + nb * 32768 + 3 * 2048);
      cp16(b1,                        dB + nb * 32768);
      cp16(b1 + (size_t)16 * LDG,     dB + nb * 32768 + 1024);
    }
    BARX; LGKM0; SCB0;
    MQ(0, 0, bf0);
    BARX;
    // ---- ph2: quadrant (0,1) ----
    LDB(buf, 1, bf1);
    BARX; LGKM0; SCB0;
    MQ(0, 1, bf1);
    BARX;
    // ---- ph3: quadrant (1,1); stage A0'(t+2) ----
    LDA(buf, 1);
    if (st2) {
      cp16(a2,                        dA + buf * 32768);
      cp16(a2 + (size_t)32 * LDG,     dA + buf * 32768 + 2048);
    }
    BARX; LGKM0; SCB0;
    MQ(1, 1, bf1);
    BARX;
    // ---- ph4: quadrant (1,0); stage B1'(t+2); the ONE wait ----
    if (st2) {
      cp16(b2 + (size_t)2 * 16 * LDG, dB + buf * 32768 + 2048);
      cp16(b2 + (size_t)3 * 16 * LDG, dB + buf * 32768 + 3072);
      WAIT4;
    } else {
      WAIT0;
    }
    BARX;
    MQ(1, 0, bf0);
    BARX;
    a1 += 64; b1 += 64; a2 += 64; b2 += 64;
  };

#pragma unroll 1
  for (int tt = 0; tt < 8; ++tt) {
    bool nl = (tt != 7);
    TILE(0, true, nl);
    TILE(1, nl, nl);
  }
}

// ---------------- stage 1 GEMM: C[row][m] = sigmoid(X.Wb^T + bb) - 0.5 (bf16) --
__global__ __launch_bounds__(512, 2) void gemm1_kernel(const u16* __restrict__ X,
                                                       const u16* __restrict__ W,
                                                       const float* __restrict__ bb,
                                                       u16* __restrict__ C,
                                                       float* __restrict__ kb) {
  __shared__ u16 lds[2 * 32768];
  int bid = blockIdx.x;                 // 512
  int xcd = bid & 7, idx = bid >> 3;    // XCD-affine: per-XCD 8 tm x 8 tn panel
  int tm = xcd * 8 + (idx & 7);         // 0..63
  int tn = idx >> 3;                    // 0..7
  int tid = threadIdx.x;
  f32x4 acc[8][4] = {};
  gemm_core<1024>(X + (size_t)tm * 256 * 1024, W + (size_t)tn * 256 * 1024,
                  lds, tid, acc);

  int lane = tid & 63, w = tid >> 6;
  int wr = w >> 2, wc = w & 3, l15 = lane & 15, quad = lane >> 4;
  int colb = tn * 256 + wc * 64 + l15;
  bool khalf = (tn >= 4);               // whole tile in k' half when tn>=4
  int rowb = tm * 256 + wr * 128 + quad * 4;
#pragma unroll
  for (int i = 0; i < 8; ++i) {
    float rsum[4] = {0.f, 0.f, 0.f, 0.f};
#pragma unroll
    for (int j = 0; j < 4; ++j) {
      int col = colb + j * 16;
      float bias = bb[col];
#pragma unroll
      for (int rg = 0; rg < 4; ++rg) {
        int row = rowb + i * 16 + rg;
        float v = acc[i][j][rg] + bias;
        float sg = 1.0f / (1.0f + __expf(-v));
        u16 h = f2bf(sg - 0.5f);
        C[(size_t)row * 2048 + col] = h;
        rsum[rg] += bf2f(h);   // rounded value, matches what flash's MFMA sees
      }
    }
    if (khalf) {
#pragma unroll
      for (int rg = 0; rg < 4; ++rg) {
        float s = rsum[rg];
#pragma unroll
        for (int off = 1; off < 16; off <<= 1) s += __shfl_xor(s, off);
        if (l15 == 0) atomicAdd(&kb[rowb + i * 16 + rg], 0.5f * s);
      }
    }
  }
}

// ---------------- flash: one 256q x 256k tile per block; XCD = batch ----
__global__ __launch_bounds__(512, 2) void flash_kernel(const u16* __restrict__ Cq,
                                                       const float* __restrict__ kb,
                                                       const float* __restrict__ r,
                                                       float* __restrict__ pm,
                                                       float* __restrict__ pl,
                                                       float* __restrict__ pt) {
  __shared__ u16 lds[2 * 32768];
  int bid = blockIdx.x;            // 512
  int b = bid & 7;                 // XCD-affine: each XCD owns one batch
  int idx = bid >> 3;
  int qt = idx >> 3;               // 0..7
  int kc = idx & 7;                // inner: q-tile reused from L2
  int tid = threadIdx.x;
  f32x4 acc[8][4] = {};
  gemm_core<2048>(Cq + (size_t)(b * SS + qt * 256) * 2048,
                  Cq + (size_t)(b * SS + kc * 256) * 2048 + 1024,
                  lds, tid, acc);

  int lane = tid & 63, w = tid >> 6;
  int wr = w >> 2, wc = w & 3, l15 = lane & 15, quad = lane >> 4;
  float kbv[4], rv[4];
  int colg = b * SS + kc * 256 + wc * 64 + l15;
#pragma unroll
  for (int j = 0; j < 4; ++j) { kbv[j] = kb[colg + j * 16]; rv[j] = r[colg + j * 16]; }
  int chunk = kc * 4 + wc;
  int rowb = b * SS + qt * 256 + wr * 128 + quad * 4;
#pragma unroll
  for (int i = 0; i < 8; ++i) {
#pragma unroll
    for (int rg = 0; rg < 4; ++rg) {
      float lg[4];
      float tmax = -1e30f;
#pragma unroll
      for (int j = 0; j < 4; ++j) { lg[j] = acc[i][j][rg] + kbv[j]; tmax = fmaxf(tmax, lg[j]); }
#pragma unroll
      for (int off = 1; off < 16; off <<= 1) tmax = fmaxf(tmax, __shfl_xor(tmax, off));
      float rs = 0.f, rt = 0.f;
#pragma unroll
      for (int j = 0; j < 4; ++j) {
        float p = __expf(lg[j] - tmax);
        rs += p; rt += p * rv[j];
      }
#pragma unroll
      for (int off = 1; off < 16; off <<= 1) { rs += __shfl_xor(rs, off); rt += __shfl_xor(rt, off); }
      if (l15 == 0) {
        int grow = rowb + i * 16 + rg;
        pm[(size_t)grow * NPC + chunk] = tmax;
        pl[(size_t)grow * NPC + chunk] = rs;
        pt[(size_t)grow * NPC + chunk] = rt;
      }
    }
  }
}

// ---------------- combine key-chunk partials ----------------
__global__ __launch_bounds__(256) void fixup_kernel(const float* __restrict__ pm,
                                                    const float* __restrict__ pl,
                                                    const float* __restrict__ pt,
                                                    float* __restrict__ out) {
  int row = blockIdx.x * 256 + threadIdx.x;
  float Mx = -1e30f;
#pragma unroll
  for (int c = 0; c < NPC; c++) Mx = fmaxf(Mx, pm[row * NPC + c]);
  float L = 0.f, T = 0.f;
#pragma unroll
  for (int c = 0; c < NPC; c++) {
    float a = __expf(pm[row * NPC + c] - Mx);
    L += pl[row * NPC + c] * a;
    T += pt[row * NPC + c] * a;
  }
  out[row] = T / L;
}

extern "C" void kernel_launch(void* const* d_in, const int* in_sizes, int n_in,
                              void* d_out, int out_size, void* d_ws, size_t ws_size,
                              hipStream_t stream) {
  const float* outer = (const float*)d_in[0];
  const float* mask  = (const float*)d_in[1];
  const float* Wk    = (const float*)d_in[2];
  const float* bk    = (const float*)d_in[3];
  const float* Wq    = (const float*)d_in[4];
  const float* bq    = (const float*)d_in[5];
  float* out = (float*)d_out;

  char* ws = (char*)d_ws;
  size_t off = 0;
  auto alloc = [&](size_t bytes) -> void* {
    void* p = ws + off;
    off = (off + bytes + 255) & ~(size_t)255;
    return p;
  };
  u16* Xb  = (u16*)alloc((size_t)MT * NN * 2);       // 32 MB bf16 outer
  u16* Wb  = (u16*)alloc((size_t)2048 * NN * 2);     // 4 MB bf16 [Wq;Wk]
  u16* Cq  = (u16*)alloc((size_t)MT * 2048 * 2);     // 64 MB bf16 [q'|k']
  float* bb = (float*)alloc(2048 * 4);
  float* rr = (float*)alloc((size_t)MT * 4);
  float* kb = (float*)alloc((size_t)MT * 4);
  float* pm = (float*)alloc((size_t)MT * NPC * 4);
  float* pl = (float*)alloc((size_t)MT * NPC * 4);
  float* pt = (float*)alloc((size_t)MT * NPC * 4);

  prep_x_kernel<<<dim3(MT / 4), dim3(256), 0, stream>>>(outer, mask, Xb, rr, kb);
  prep_w_kernel<<<dim3(2048), dim3(256), 0, stream>>>(Wq, Wk, bq, bk, Wb, bb);
  gemm1_kernel<<<dim3(512), dim3(512), 0, stream>>>(Xb, Wb, bb, Cq, kb);
  flash_kernel<<<dim3(512), dim3(512), 0, stream>>>(Cq, kb, rr, pm, pl, pt);
  fixup_kernel<<<dim3(MT / 256), dim3(256), 0, stream>>>(pm, pl, pt, out);
}